// Round 5
// baseline (491.321 us; speedup 1.0000x reference)
//
#include <hip/hip_runtime.h>
#include <stdint.h>

typedef int int32x4 __attribute__((ext_vector_type(4)));

#define M_ROWS 8192
#define K_DIM  4096
#define N_DIM  4096

#define GPTR(p) ((const __attribute__((address_space(1))) unsigned int*)(p))
#define LPTR(p) ((__attribute__((address_space(3))) unsigned int*)(p))

// ---------- shared helper: block-wide absmax over 256 threads ----------
__device__ __forceinline__ float block_absmax_256(float v, float* red) {
#pragma unroll
  for (int off = 32; off > 0; off >>= 1)
    v = fmaxf(v, __shfl_down(v, off, 64));
  const int w = threadIdx.x >> 6;
  if ((threadIdx.x & 63) == 0) red[w] = v;
  __syncthreads();
  return fmaxf(fmaxf(red[0], red[1]), fmaxf(red[2], red[3]));
}

// ---------- 1. fused prep: quant_x | colmax partials | bias int16 quant ----------
__global__ void prep_kernel(const float* __restrict__ x,
                            const float* __restrict__ kern,
                            const float* __restrict__ bias,
                            int8_t* __restrict__ qx,
                            float* __restrict__ sx,
                            float* __restrict__ pm,
                            float* __restrict__ bq) {
  __shared__ float red[4];
  const int t = threadIdx.x;
  const int b = blockIdx.x;

  if (b < M_ROWS) {
    const float* xr = x + (size_t)b * K_DIM;
    float4 v[4];
    float m = 0.0f;
#pragma unroll
    for (int i = 0; i < 4; ++i) {
      v[i] = *(const float4*)(xr + i * 1024 + t * 4);
      m = fmaxf(m, fmaxf(fmaxf(fabsf(v[i].x), fabsf(v[i].y)),
                         fmaxf(fabsf(v[i].z), fabsf(v[i].w))));
    }
    float amax = block_absmax_256(m, red);
    float scale = amax / 127.0f;
    if (scale == 0.0f) scale = 1.0f;
    if (t == 0) sx[b] = scale;
#pragma unroll
    for (int i = 0; i < 4; ++i) {
      float a = fminf(fmaxf(v[i].x / scale, -127.0f), 127.0f);
      float bb = fminf(fmaxf(v[i].y / scale, -127.0f), 127.0f);
      float c = fminf(fmaxf(v[i].z / scale, -127.0f), 127.0f);
      float d = fminf(fmaxf(v[i].w / scale, -127.0f), 127.0f);
      int qa = (int)rintf(a), qb = (int)rintf(bb), qc = (int)rintf(c), qd = (int)rintf(d);
      int word = (qa & 255) | ((qb & 255) << 8) | ((qc & 255) << 16) | ((qd & 255) << 24);
      *(int*)(qx + (size_t)b * K_DIM + i * 1024 + t * 4) = word;
    }
  } else if (b < M_ROWS + 512) {
    const int bb = b - M_ROWS;
    const int c = (bb & 15) * 256 + t;
    const int r0 = (bb >> 4) * 128;
    float m = 0.0f;
    for (int i = 0; i < 128; ++i)
      m = fmaxf(m, fabsf(kern[(size_t)(r0 + i) * N_DIM + c]));
    pm[(size_t)(bb >> 4) * N_DIM + c] = m;
  } else {
    float4 v[4];
    float m = 0.0f;
#pragma unroll
    for (int i = 0; i < 4; ++i) {
      v[i] = *(const float4*)(bias + i * 1024 + t * 4);
      m = fmaxf(m, fmaxf(fmaxf(fabsf(v[i].x), fabsf(v[i].y)),
                         fmaxf(fabsf(v[i].z), fabsf(v[i].w))));
    }
    float amax = block_absmax_256(m, red);
    float s = amax / 32767.0f;
    if (s == 0.0f) s = 1.0f;
#pragma unroll
    for (int i = 0; i < 4; ++i) {
      float4 o;
      o.x = rintf(fminf(fmaxf(v[i].x / s, -32767.0f), 32767.0f)) * s;
      o.y = rintf(fminf(fmaxf(v[i].y / s, -32767.0f), 32767.0f)) * s;
      o.z = rintf(fminf(fmaxf(v[i].z / s, -32767.0f), 32767.0f)) * s;
      o.w = rintf(fminf(fmaxf(v[i].w / s, -32767.0f), 32767.0f)) * s;
      *(float4*)(bq + i * 1024 + t * 4) = o;
    }
  }
}

// ---------- 2. quantize kernel per-col and transpose -> qkT[F][D] int8 ----------
__global__ void quant_kT_kernel(const float* __restrict__ kern,
                                const float* __restrict__ pm,
                                float* __restrict__ sk,
                                int8_t* __restrict__ qkT) {
  __shared__ int8_t tile[64][80];
  __shared__ float skl[64];
  const int t = threadIdx.x;
  const int c0 = blockIdx.x * 64;
  const int r0 = blockIdx.y * 64;
  if (t < 64) {
    float m = 0.0f;
#pragma unroll
    for (int i = 0; i < 32; ++i) m = fmaxf(m, pm[(size_t)i * N_DIM + c0 + t]);
    float s = m / 127.0f;
    if (s == 0.0f) s = 1.0f;
    skl[t] = s;
    if (blockIdx.y == 0) sk[c0 + t] = s;
  }
  __syncthreads();
  const int colg = (t & 15) * 4;
  const int row = t >> 4;
  float s[4];
#pragma unroll
  for (int j = 0; j < 4; ++j) s[j] = skl[colg + j];
#pragma unroll
  for (int i = 0; i < 4; ++i) {
    const int r = row + i * 16;
    float4 v = *(const float4*)&kern[(size_t)(r0 + r) * N_DIM + c0 + colg];
    tile[colg + 0][r] = (int8_t)rintf(fminf(fmaxf(v.x / s[0], -127.0f), 127.0f));
    tile[colg + 1][r] = (int8_t)rintf(fminf(fmaxf(v.y / s[1], -127.0f), 127.0f));
    tile[colg + 2][r] = (int8_t)rintf(fminf(fmaxf(v.z / s[2], -127.0f), 127.0f));
    tile[colg + 3][r] = (int8_t)rintf(fminf(fmaxf(v.w / s[3], -127.0f), 127.0f));
  }
  __syncthreads();
  const int f = t >> 2;
  const int seg = (t & 3) * 16;
  int4 w = *(const int4*)&tile[f][seg];
  *(int4*)(qkT + (size_t)(c0 + f) * K_DIM + r0 + seg) = w;
}

// ---------- 3. int8 GEMM: BK=64 double-buffer, 32 KiB LDS total,
//             1 barrier per 64-K phase, prefetch distance = 1 phase ----------
// R2's occupancy (32 KiB -> 5 blocks/CU LDS-limit) + R4's prefetch overlap.
#define BM 128
#define BN 128

__global__ void gemm_kernel(const int8_t* __restrict__ qx,
                            const int8_t* __restrict__ qkT,
                            const float* __restrict__ sx,
                            const float* __restrict__ sk,
                            const float* __restrict__ bq,
                            float* __restrict__ out) {
  __shared__ int32x4 AsV[1024];  // 2 buffers x 8 KiB: A half-tile [128 rows][64 B]
  __shared__ int32x4 BsV[1024];  // 2 buffers x 8 KiB
  char* As = (char*)AsV;
  char* Bs = (char*)BsV;

  const int t = threadIdx.x;
  const int w = t >> 6;
  const int l = t & 63;
  const int wm = w >> 1, wn = w & 1;
  const int rowBase = blockIdx.y * BM;
  const int colBase = blockIdx.x * BN;

  // 64-B rows, 4 slots of 16 B, XOR swizzle: global k-chunk g at slot
  // g ^ (row & 3). Staging lane l -> row l>>2, slot l&3 -> global chunk
  // (l&3)^((l>>2)&3). (R1 pattern: conflict counter shows only the benign
  // 4-cyc/b128 baseline.)
  const int8_t* gA = qx  + (size_t)(rowBase + (l >> 2)) * K_DIM
                         + (((l & 3) ^ ((l >> 2) & 3)) * 16);
  const int8_t* gB = qkT + (size_t)(colBase + (l >> 2)) * K_DIM
                         + (((l & 3) ^ ((l >> 2) & 3)) * 16);

  // Frag reads: row = l&15, logical k-slot l>>4 -> phys slot (l>>4)^(l&3).
  int arow[4], brow[4];
#pragma unroll
  for (int mt = 0; mt < 4; ++mt)
    arow[mt] = (wm * 64 + mt * 16 + (l & 15)) * 64;
#pragma unroll
  for (int nt = 0; nt < 4; ++nt)
    brow[nt] = (wn * 64 + nt * 16 + (l & 15)) * 64;
  const int soff = ((l >> 4) ^ (l & 3)) * 16;

  int32x4 zero = {0, 0, 0, 0};
  int32x4 acc[4][4];
#pragma unroll
  for (int mt = 0; mt < 4; ++mt)
#pragma unroll
    for (int nt = 0; nt < 4; ++nt) acc[mt][nt] = zero;

  // prologue: stage phase 0 into buffer 0
#pragma unroll
  for (int j = 0; j < 2; ++j) {
    const int ca = j * 4 + w;  // 8 chunks of 16 rows x 64 B
    __builtin_amdgcn_global_load_lds(GPTR(gA + (size_t)ca * 16 * K_DIM),
                                     LPTR(As + ca * 1024), 16, 0, 0);
    __builtin_amdgcn_global_load_lds(GPTR(gB + (size_t)ca * 16 * K_DIM),
                                     LPTR(Bs + ca * 1024), 16, 0, 0);
  }

  for (int k0 = 0; k0 < K_DIM; k0 += 64) {
    const int p = (k0 >> 6) & 1;
    const int pb = p * 8192;
    // One barrier per phase: ensures (a) all waves done reading buf p^1
    // (last read one phase ago) and (b) vmcnt drain of buf-p loads, which
    // were issued one full compute phase earlier.
    __syncthreads();

    if (k0 + 64 < K_DIM) {
      const int qb = (p ^ 1) * 8192;
#pragma unroll
      for (int j = 0; j < 2; ++j) {
        const int ca = j * 4 + w;
        __builtin_amdgcn_global_load_lds(
            GPTR(gA + (size_t)ca * 16 * K_DIM + k0 + 64),
            LPTR(As + qb + ca * 1024), 16, 0, 0);
        __builtin_amdgcn_global_load_lds(
            GPTR(gB + (size_t)ca * 16 * K_DIM + k0 + 64),
            LPTR(Bs + qb + ca * 1024), 16, 0, 0);
      }
    }

    int32x4 af[4], bf[4];
#pragma unroll
    for (int mt = 0; mt < 4; ++mt)
      af[mt] = *(const int32x4*)(As + pb + arow[mt] + soff);
#pragma unroll
    for (int nt = 0; nt < 4; ++nt)
      bf[nt] = *(const int32x4*)(Bs + pb + brow[nt] + soff);
#pragma unroll
    for (int mt = 0; mt < 4; ++mt)
#pragma unroll
      for (int nt = 0; nt < 4; ++nt)
        acc[mt][nt] = __builtin_amdgcn_mfma_i32_16x16x64_i8(
            af[mt], bf[nt], acc[mt][nt], 0, 0, 0);
  }

  // epilogue: y = acc * sx[row] * sk[col] + bq[col]
  const int lr = (l >> 4) * 4;
  const int lc = l & 15;
#pragma unroll
  for (int mt = 0; mt < 4; ++mt) {
    const int r0 = rowBase + wm * 64 + mt * 16 + lr;
    float sxr[4];
#pragma unroll
    for (int r = 0; r < 4; ++r) sxr[r] = sx[r0 + r];
#pragma unroll
    for (int nt = 0; nt < 4; ++nt) {
      const int c = colBase + wn * 64 + nt * 16 + lc;
      const float skc = sk[c];
      const float bqc = bq[c];
#pragma unroll
      for (int r = 0; r < 4; ++r)
        out[(size_t)(r0 + r) * N_DIM + c] =
            (float)acc[mt][nt][r] * (sxr[r] * skc) + bqc;
    }
  }
}

// ---------- 4. per-row int8 requant of output (in place) ----------
__global__ void requant_kernel(float* __restrict__ y) {
  __shared__ float red[4];
  const int row = blockIdx.x;
  const int t = threadIdx.x;
  float* yr = y + (size_t)row * N_DIM;
  float4 v[4];
  float m = 0.0f;
#pragma unroll
  for (int i = 0; i < 4; ++i) {
    v[i] = *(const float4*)(yr + i * 1024 + t * 4);
    m = fmaxf(m, fmaxf(fmaxf(fabsf(v[i].x), fabsf(v[i].y)),
                       fmaxf(fabsf(v[i].z), fabsf(v[i].w))));
  }
  float amax = block_absmax_256(m, red);
  float s = amax / 127.0f;
  if (s == 0.0f) s = 1.0f;
#pragma unroll
  for (int i = 0; i < 4; ++i) {
    float4 o;
    o.x = rintf(fminf(fmaxf(v[i].x / s, -127.0f), 127.0f)) * s;
    o.y = rintf(fminf(fmaxf(v[i].y / s, -127.0f), 127.0f)) * s;
    o.z = rintf(fminf(fmaxf(v[i].z / s, -127.0f), 127.0f)) * s;
    o.w = rintf(fminf(fmaxf(v[i].w / s, -127.0f), 127.0f)) * s;
    *(float4*)(yr + i * 1024 + t * 4) = o;
  }
}

extern "C" void kernel_launch(void* const* d_in, const int* in_sizes, int n_in,
                              void* d_out, int out_size, void* d_ws, size_t ws_size,
                              hipStream_t stream) {
  (void)in_sizes; (void)n_in; (void)out_size; (void)ws_size;
  const float* x    = (const float*)d_in[0];
  const float* kern = (const float*)d_in[1];
  const float* bias = (const float*)d_in[2];
  float* out = (float*)d_out;

  char* w8 = (char*)d_ws;
  int8_t* qx  = (int8_t*)w8;                       // 32 MiB
  int8_t* qkT = (int8_t*)(w8 + 33554432);          // 16 MiB
  float* sx   = (float*)(w8 + 50331648);           // 8192 f
  float* sk   = (float*)(w8 + 50331648 + 49152);   // 4096 f
  float* bq   = (float*)(w8 + 50331648 + 65536);   // 4096 f
  float* pm   = (float*)(w8 + 50331648 + 131072);  // 32*4096 f partial colmax

  prep_kernel<<<M_ROWS + 512 + 1, 256, 0, stream>>>(x, kern, bias, qx, sx, pm, bq);
  quant_kT_kernel<<<dim3(64, 64), 256, 0, stream>>>(kern, pm, sk, qkT);
  gemm_kernel<<<dim3(N_DIM / BN, M_ROWS / BM), 256, 0, stream>>>(qx, qkT, sx, sk, bq, out);
  requant_kernel<<<M_ROWS, 256, 0, stream>>>(out);
}